// Round 1
// baseline (1329.228 us; speedup 1.0000x reference)
//
#include <hip/hip_runtime.h>

typedef unsigned short u16;
typedef unsigned int   u32;
typedef __attribute__((ext_vector_type(4))) u16   u16x4;
typedef __attribute__((ext_vector_type(8))) u16   u16x8;
typedef __attribute__((ext_vector_type(8))) __bf16 bf16x8;
typedef __attribute__((ext_vector_type(4))) float f32x4;

#define DEV static __device__ __forceinline__

constexpr int DIM = 512, NHEAD = 8, DHEAD = 64, DFFN = 2048, NLAY = 6, SEQ = 512, BATCH = 8;
constexpr int MROWS = BATCH * SEQ;            // 4096 token rows
constexpr long HD = (long)SEQ * DHEAD;        // 32768 per-head q/k/v block
constexpr long SS = (long)SEQ * SEQ;          // 262144 per-head score block

DEV float bf2f(u16 u) { union { u32 i; float f; } x; x.i = (u32)u << 16; return x.f; }
DEV u16 f2bf(float f) { union { float f; u32 i; } x; x.f = f; u32 r = x.i + 0x7fffu + ((x.i >> 16) & 1u); return (u16)(r >> 16); }

// ---------------------------------------------------------------------------
// Weight transpose + f32->bf16:  out[l][n][k] = bf16(in[l][k][n])
// ---------------------------------------------------------------------------
__global__ __launch_bounds__(256) void transpose_w(const float* __restrict__ in, u16* __restrict__ out,
                                                   int K, int N)
{
    __shared__ u16 t[32][33];
    long base = (long)blockIdx.z * K * N;
    int k0 = blockIdx.y * 32, n0 = blockIdx.x * 32;
    int tx = threadIdx.x & 31, ty = threadIdx.x >> 5;
    #pragma unroll
    for (int i = ty; i < 32; i += 8) t[i][tx] = f2bf(in[base + (long)(k0 + i) * N + n0 + tx]);
    __syncthreads();
    #pragma unroll
    for (int i = ty; i < 32; i += 8) out[base + (long)(n0 + i) * K + k0 + tx] = t[tx][i];
}

// ---------------------------------------------------------------------------
// f32 -> bf16 for the encoder memory (exactly 2M elements)
// ---------------------------------------------------------------------------
__global__ __launch_bounds__(256) void conv_f32_bf16(const float* __restrict__ in, u16* __restrict__ out)
{
    long i = ((long)blockIdx.x * 256 + threadIdx.x) * 4;
    float4 v = *(const float4*)(in + i);
    u16x4 o; o.x = f2bf(v.x); o.y = f2bf(v.y); o.z = f2bf(v.z); o.w = f2bf(v.w);
    *(u16x4*)(out + i) = o;
}

// ---------------------------------------------------------------------------
// Embedding * sqrt(D) + sinusoidal positional encoding -> x (f32) and xb (bf16)
// ---------------------------------------------------------------------------
__global__ __launch_bounds__(256) void embed_pe(const int* __restrict__ targets, const float* __restrict__ emb,
                                                float* __restrict__ x, u16* __restrict__ xb)
{
    int t4 = (blockIdx.x * 256 + threadIdx.x) * 4;
    int d = t4 & (DIM - 1);
    int s = (t4 >> 9) & (SEQ - 1);
    int b = t4 >> 18;
    int tok = targets[s * BATCH + b];
    float4 e = *(const float4*)(emb + (long)tok * DIM + d);
    float o[4]; u16x4 ob;
    const float ef[4] = { e.x, e.y, e.z, e.w };
    #pragma unroll
    for (int j = 0; j < 4; ++j) {
        int dd = d + j;
        float div = expf((float)(dd & ~1) * -0.017988946039016f);  // -ln(10000)/512
        float ang = (float)s * div;
        float pe = (dd & 1) ? cosf(ang) : sinf(ang);
        float val = ef[j] * 22.627416997969522f + pe;              // sqrt(512)
        o[j] = val; ob[j] = f2bf(val);
    }
    long idx = ((long)b * SEQ + s) * DIM + d;
    *(float4*)(x + idx) = *(const float4*)o;
    *(u16x4*)(xb + idx) = ob;
}

// ---------------------------------------------------------------------------
// GEMM: C = A @ Bt^T (+bias, +relu).  A: MxK bf16 (lda=K), Bt: NxK bf16 (ldb=K).
// 64x64 tile, 4 waves, mfma_f32_16x16x32_bf16.
// EPI: 0 = f32 plain, 1 = bf16 plain, 2 = bf16 scatter to (B,NH,S,DH),
//      3 = bf16 scatter to (B,NH,DH,S).
// C batch offset: (z/cDiv)*cOut + (z%cDiv)*cIn.
// ---------------------------------------------------------------------------
template <int EPI, bool RELU, bool BIAS>
__global__ __launch_bounds__(256) void gemm_bt(const u16* __restrict__ A, const u16* __restrict__ Bt,
                                               void* __restrict__ C, const float* __restrict__ bias,
                                               int M, int N, int K,
                                               long aB, long bB, long cOut, long cIn, int cDiv, int ldc)
{
    __shared__ __align__(16) u16 As[64][40];   // +8 pad: kills stride-64B bank conflicts
    __shared__ __align__(16) u16 Bs[64][40];
    const int tid = threadIdx.x, lane = tid & 63, wid = tid >> 6;
    const int m0 = blockIdx.y * 64, n0 = blockIdx.x * 64, z = blockIdx.z;
    const u16* Ab = A + (long)z * aB;
    const u16* Bb = Bt + (long)z * bB;
    const int r  = tid >> 2, c4 = (tid & 3) * 8;       // staging: row r, 8-elem chunk
    const int wr = (wid >> 1) * 32, wc = (wid & 1) * 32; // wave quadrant
    const int fr = lane & 15, kg = (lane >> 4) * 8, fq = lane >> 4;

    f32x4 acc[2][2] = {};
    u16x8 av = *(const u16x8*)(Ab + (long)(m0 + r) * K + c4);
    u16x8 bv = *(const u16x8*)(Bb + (long)(n0 + r) * K + c4);

    for (int k0 = 0; k0 < K; k0 += 32) {
        __syncthreads();
        *(u16x8*)&As[r][c4] = av;
        *(u16x8*)&Bs[r][c4] = bv;
        if (k0 + 32 < K) {
            av = *(const u16x8*)(Ab + (long)(m0 + r) * K + (k0 + 32) + c4);
            bv = *(const u16x8*)(Bb + (long)(n0 + r) * K + (k0 + 32) + c4);
        }
        __syncthreads();
        bf16x8 a0 = *(const bf16x8*)&As[wr + fr][kg];
        bf16x8 a1 = *(const bf16x8*)&As[wr + 16 + fr][kg];
        bf16x8 b0 = *(const bf16x8*)&Bs[wc + fr][kg];
        bf16x8 b1 = *(const bf16x8*)&Bs[wc + 16 + fr][kg];
        acc[0][0] = __builtin_amdgcn_mfma_f32_16x16x32_bf16(a0, b0, acc[0][0], 0, 0, 0);
        acc[0][1] = __builtin_amdgcn_mfma_f32_16x16x32_bf16(a0, b1, acc[0][1], 0, 0, 0);
        acc[1][0] = __builtin_amdgcn_mfma_f32_16x16x32_bf16(a1, b0, acc[1][0], 0, 0, 0);
        acc[1][1] = __builtin_amdgcn_mfma_f32_16x16x32_bf16(a1, b1, acc[1][1], 0, 0, 0);
    }

    const long cb = (long)(z / cDiv) * cOut + (long)(z % cDiv) * cIn;
    #pragma unroll
    for (int mi = 0; mi < 2; ++mi)
    #pragma unroll
    for (int ni = 0; ni < 2; ++ni)
    #pragma unroll
    for (int rr = 0; rr < 4; ++rr) {
        int mm = m0 + wr + mi * 16 + fq * 4 + rr;   // C row   (verified m89/m91 layout)
        int nn = n0 + wc + ni * 16 + fr;            // C col
        float v = acc[mi][ni][rr];
        if (BIAS) v += bias[nn];
        if (RELU) v = fmaxf(v, 0.f);
        if (EPI == 0) {
            ((float*)C)[cb + (long)mm * ldc + nn] = v;
        } else if (EPI == 1) {
            ((u16*)C)[cb + (long)mm * ldc + nn] = f2bf(v);
        } else if (EPI == 2) {      // (B*S, D) -> (B,NH,S,DH)
            ((u16*)C)[(long)((mm >> 9) * NHEAD + (nn >> 6)) * HD + (mm & 511) * DHEAD + (nn & 63)] = f2bf(v);
        } else {                    // (B*S, D) -> (B,NH,DH,S)
            ((u16*)C)[(long)((mm >> 9) * NHEAD + (nn >> 6)) * HD + (nn & 63) * SEQ + (mm & 511)] = f2bf(v);
        }
    }
}

// ---------------------------------------------------------------------------
// Row softmax over bf16 scores (in-place), scale 1/8, optional causal mask.
// One wave per row of 512.
// ---------------------------------------------------------------------------
__global__ __launch_bounds__(256) void softmax_rows(u16* __restrict__ att, int causal)
{
    int row = blockIdx.x * 4 + (threadIdx.x >> 6);
    int lane = threadIdx.x & 63;
    int q = row & (SEQ - 1);
    u16* p = att + (long)row * SEQ + lane * 8;
    u16x8 v = *(u16x8*)p;
    float f[8], mx = -3.0e38f;
    #pragma unroll
    for (int j = 0; j < 8; ++j) {
        int col = lane * 8 + j;
        float s = bf2f(v[j]) * 0.125f;               // 1/sqrt(64)
        if (causal && col > q) s = -3.0e38f;
        f[j] = s; mx = fmaxf(mx, s);
    }
    #pragma unroll
    for (int o = 32; o; o >>= 1) mx = fmaxf(mx, __shfl_xor(mx, o, 64));
    float sum = 0.f;
    #pragma unroll
    for (int j = 0; j < 8; ++j) { f[j] = __expf(f[j] - mx); sum += f[j]; }
    #pragma unroll
    for (int o = 32; o; o >>= 1) sum += __shfl_xor(sum, o, 64);
    float inv = 1.0f / sum;
    u16x8 ov;
    #pragma unroll
    for (int j = 0; j < 8; ++j) ov[j] = f2bf(f[j] * inv);
    *(u16x8*)p = ov;
}

// ---------------------------------------------------------------------------
// x = LayerNorm(x + y) * g + be;  writes f32 (xo) and bf16 (xb). One wave/row.
// (x and xo may alias -> no restrict on them; row fully read before written.)
// ---------------------------------------------------------------------------
__global__ __launch_bounds__(256) void add_ln(const float* x, const float* __restrict__ y,
                                              float* xo, u16* __restrict__ xb,
                                              const float* __restrict__ g, const float* __restrict__ be)
{
    int row = blockIdx.x * 4 + (threadIdx.x >> 6);
    int lane = threadIdx.x & 63;
    long off = (long)row * DIM + lane * 8;
    float v[8];
    {
        float4 a0 = *(const float4*)(x + off);
        float4 a1 = *(const float4*)(x + off + 4);
        float4 b0 = *(const float4*)(y + off);
        float4 b1 = *(const float4*)(y + off + 4);
        v[0] = a0.x + b0.x; v[1] = a0.y + b0.y; v[2] = a0.z + b0.z; v[3] = a0.w + b0.w;
        v[4] = a1.x + b1.x; v[5] = a1.y + b1.y; v[6] = a1.z + b1.z; v[7] = a1.w + b1.w;
    }
    float sum = 0.f;
    #pragma unroll
    for (int j = 0; j < 8; ++j) sum += v[j];
    #pragma unroll
    for (int o = 32; o; o >>= 1) sum += __shfl_xor(sum, o, 64);
    float mean = sum * (1.0f / DIM);
    float vs = 0.f;
    #pragma unroll
    for (int j = 0; j < 8; ++j) { float d = v[j] - mean; vs += d * d; }
    #pragma unroll
    for (int o = 32; o; o >>= 1) vs += __shfl_xor(vs, o, 64);
    float rstd = rsqrtf(vs * (1.0f / DIM) + 1e-5f);
    float outv[8]; u16x8 ob;
    #pragma unroll
    for (int j = 0; j < 8; ++j) {
        int col = lane * 8 + j;
        float r = (v[j] - mean) * rstd * g[col] + be[col];
        outv[j] = r; ob[j] = f2bf(r);
    }
    *(float4*)(xo + off)     = *(const float4*)&outv[0];
    *(float4*)(xo + off + 4) = *(const float4*)&outv[4];
    *(u16x8*)(xb + off) = ob;
}

// ---------------------------------------------------------------------------
extern "C" void kernel_launch(void* const* d_in, const int* in_sizes, int n_in,
                              void* d_out, int out_size, void* d_ws, size_t ws_size,
                              hipStream_t stream)
{
    const int*   targets = (const int*)  d_in[0];
    const float* memory  = (const float*)d_in[1];
    // d_in[2]=trg_mask (causal, analytic), d_in[3]=memory_mask (all false) -> unread
    const float* emb     = (const float*)d_in[4];
    const float* Wg[8]; for (int i = 0; i < 8; ++i) Wg[i] = (const float*)d_in[5 + i];
    const float* bg[8]; for (int i = 0; i < 8; ++i) bg[i] = (const float*)d_in[13 + i];
    const float* W1  = (const float*)d_in[21];
    const float* b1  = (const float*)d_in[22];
    const float* W2  = (const float*)d_in[23];
    const float* b2  = (const float*)d_in[24];
    const float* g1  = (const float*)d_in[25];
    const float* g2  = (const float*)d_in[26];
    const float* g3  = (const float*)d_in[27];
    const float* be1 = (const float*)d_in[28];
    const float* be2 = (const float*)d_in[29];
    const float* be3 = (const float*)d_in[30];

    char* w = (char*)d_ws;
    auto take = [&](size_t n) -> char* { char* p = w; w += (n + 255) & ~(size_t)255; return p; };
    u16* wT[8]; for (int i = 0; i < 8; ++i) wT[i] = (u16*)take((size_t)NLAY * DIM * DIM * 2);
    u16*   w1T  = (u16*)  take((size_t)NLAY * DIM * DFFN * 2);
    u16*   w2T  = (u16*)  take((size_t)NLAY * DIM * DFFN * 2);
    float* x    = (float*)take((size_t)MROWS * DIM * 4);
    float* y    = (float*)take((size_t)MROWS * DIM * 4);
    u16*   xb   = (u16*)  take((size_t)MROWS * DIM * 2);
    u16*   memb = (u16*)  take((size_t)MROWS * DIM * 2);
    u16*   qh   = (u16*)  take((size_t)MROWS * DIM * 2);
    u16*   kh   = (u16*)  take((size_t)MROWS * DIM * 2);
    u16*   vT   = (u16*)  take((size_t)MROWS * DIM * 2);
    u16*   ctx  = (u16*)  take((size_t)MROWS * DIM * 2);
    u16*   att  = (u16*)  take((size_t)BATCH * NHEAD * SEQ * SEQ * 2);
    u16*   h1   = att;   // FFN hidden (16MB) aliases attention buffer (33.5MB): disjoint lifetimes

    for (int i = 0; i < 8; ++i)
        transpose_w<<<dim3(16, 16, NLAY), 256, 0, stream>>>(Wg[i], wT[i], DIM, DIM);
    transpose_w<<<dim3(DFFN / 32, 16, NLAY), 256, 0, stream>>>(W1, w1T, DIM, DFFN);
    transpose_w<<<dim3(16, DFFN / 32, NLAY), 256, 0, stream>>>(W2, w2T, DFFN, DIM);
    conv_f32_bf16<<<2048, 256, 0, stream>>>(memory, memb);
    embed_pe<<<2048, 256, 0, stream>>>(targets, emb, x, xb);

    for (int i = 0; i < NLAY; ++i) {
        const long wOff = (long)i * DIM * DIM;
        const u16 *wq = wT[0] + wOff, *wk = wT[1] + wOff, *wv = wT[2] + wOff, *wo = wT[3] + wOff;
        const u16 *wqc = wT[4] + wOff, *wkc = wT[5] + wOff, *wvc = wT[6] + wOff, *woc = wT[7] + wOff;
        const float *bq = bg[0] + i * DIM, *bk = bg[1] + i * DIM, *bv = bg[2] + i * DIM, *bo = bg[3] + i * DIM;
        const float *bqc = bg[4] + i * DIM, *bkc = bg[5] + i * DIM, *bvc = bg[6] + i * DIM, *boc = bg[7] + i * DIM;
        const u16 *w1t = w1T + (long)i * DIM * DFFN, *w2t = w2T + (long)i * DIM * DFFN;

        // ---- self attention (causal) ----
        gemm_bt<2, false, true><<<dim3(8, 64, 1), 256, 0, stream>>>(xb, wq, qh, bq, MROWS, DIM, DIM, 0, 0, 0, 0, 1, 0);
        gemm_bt<2, false, true><<<dim3(8, 64, 1), 256, 0, stream>>>(xb, wk, kh, bk, MROWS, DIM, DIM, 0, 0, 0, 0, 1, 0);
        gemm_bt<3, false, true><<<dim3(8, 64, 1), 256, 0, stream>>>(xb, wv, vT, bv, MROWS, DIM, DIM, 0, 0, 0, 0, 1, 0);
        gemm_bt<1, false, false><<<dim3(8, 8, 64), 256, 0, stream>>>(qh, kh, att, nullptr, SEQ, SEQ, DHEAD, HD, HD, SS, 0, 1, SEQ);
        softmax_rows<<<(BATCH * NHEAD * SEQ) / 4, 256, 0, stream>>>(att, 1);
        gemm_bt<1, false, false><<<dim3(1, 8, 64), 256, 0, stream>>>(att, vT, ctx, nullptr, SEQ, DHEAD, SEQ, SS, HD, (long)SEQ * DIM, DHEAD, NHEAD, DIM);
        gemm_bt<0, false, true><<<dim3(8, 64, 1), 256, 0, stream>>>(ctx, wo, y, bo, MROWS, DIM, DIM, 0, 0, 0, 0, 1, DIM);
        add_ln<<<MROWS / 4, 256, 0, stream>>>(x, y, x, xb, g1 + i * DIM, be1 + i * DIM);

        // ---- cross attention (no mask) ----
        gemm_bt<2, false, true><<<dim3(8, 64, 1), 256, 0, stream>>>(xb, wqc, qh, bqc, MROWS, DIM, DIM, 0, 0, 0, 0, 1, 0);
        gemm_bt<2, false, true><<<dim3(8, 64, 1), 256, 0, stream>>>(memb, wkc, kh, bkc, MROWS, DIM, DIM, 0, 0, 0, 0, 1, 0);
        gemm_bt<3, false, true><<<dim3(8, 64, 1), 256, 0, stream>>>(memb, wvc, vT, bvc, MROWS, DIM, DIM, 0, 0, 0, 0, 1, 0);
        gemm_bt<1, false, false><<<dim3(8, 8, 64), 256, 0, stream>>>(qh, kh, att, nullptr, SEQ, SEQ, DHEAD, HD, HD, SS, 0, 1, SEQ);
        softmax_rows<<<(BATCH * NHEAD * SEQ) / 4, 256, 0, stream>>>(att, 0);
        gemm_bt<1, false, false><<<dim3(1, 8, 64), 256, 0, stream>>>(att, vT, ctx, nullptr, SEQ, DHEAD, SEQ, SS, HD, (long)SEQ * DIM, DHEAD, NHEAD, DIM);
        gemm_bt<0, false, true><<<dim3(8, 64, 1), 256, 0, stream>>>(ctx, woc, y, boc, MROWS, DIM, DIM, 0, 0, 0, 0, 1, DIM);
        add_ln<<<MROWS / 4, 256, 0, stream>>>(x, y, x, xb, g2 + i * DIM, be2 + i * DIM);

        // ---- FFN ----
        gemm_bt<1, true, true><<<dim3(DFFN / 64, 64, 1), 256, 0, stream>>>(xb, w1t, h1, b1 + i * DFFN, MROWS, DFFN, DIM, 0, 0, 0, 0, 1, DFFN);
        gemm_bt<0, false, true><<<dim3(8, 64, 1), 256, 0, stream>>>(h1, w2t, y, b2 + i * DIM, MROWS, DIM, DFFN, 0, 0, 0, 0, 1, DIM);
        float* xo = (i == NLAY - 1) ? (float*)d_out : x;
        add_ln<<<MROWS / 4, 256, 0, stream>>>(x, y, xo, xb, g3 + i * DIM, be3 + i * DIM);
    }
}